// Round 7
// baseline (273.999 us; speedup 1.0000x reference)
//
#include <hip/hip_runtime.h>
#include <hip/hip_bf16.h>

// out[b,j] = sum_{i,k} coef[j,i,k] * tanh(x[b,i])^k
// B=8192, IN=1024, OUT=1024, ORDER=7.
// k=0 plane -> per-j bias (computed in prep, added in gemm epilogue).
// GEMM: M=8192, N=1024, K=IN*7=7168, bf16 MFMA.
//
// Round 7: BK=128 (64 MFMA per barrier-pair, 2x the BK=64 amortization).
// LDS 64 KB/block; occupancy stays 2 blocks/CU (grid-capped at 512 blocks).
// XOR swizzle generalized to 16 chunks/row: slot s of row m holds global
// chunk s^(m&15) -> compute reads hit each 4-bank group 2x (free).
// Grid dims swapped (blockIdx.x = n-tile) so id%8 = n-tile -> per-XCD
// L2-resident B slice.

#define BM 128
#define BN 128
#define BK 128
#define KT 7168
#define KFULL 8192

typedef short bf16x8 __attribute__((ext_vector_type(8)));
typedef short bf16x4 __attribute__((ext_vector_type(4)));
typedef float f32x4  __attribute__((ext_vector_type(4)));

__device__ __forceinline__ unsigned short f2bf(float f) {
    union { float f; unsigned u; } v; v.f = f;
    unsigned r = v.u + 0x7fffu + ((v.u >> 16) & 1u);   // RTE
    return (unsigned short)(r >> 16);
}

__device__ __forceinline__ void gload_lds16(const void* gp, void* lp) {
    __builtin_amdgcn_global_load_lds(
        (const __attribute__((address_space(1))) void*)gp,
        (__attribute__((address_space(3))) void*)lp, 16, 0, 0);
}

// ---- pass 1: prep (unchanged from round 6) ----
#define CVT_BLOCKS  512
#define TANH_BLOCKS 4096

__global__ __launch_bounds__(256)
void prep(const float* __restrict__ x, const float* __restrict__ trp,
          const float* __restrict__ coef, unsigned short* __restrict__ coef_bf,
          unsigned short* __restrict__ A, float* __restrict__ bias) {
    __shared__ unsigned short st[256 * 56];   // 28672 B
    __shared__ float redbuf[4];

    const int t   = threadIdx.x;
    const int blk = blockIdx.x;
    const int rl  = t >> 7;        // row_local 0/1
    const int ig  = t & 127;       // i-group (8 i's each)
    const bool is_cvt = (blk < CVT_BLOCKS);

    unsigned short tmp[56];

    if (is_cvt) {
        const int j = blk * 2 + rl;
        const float* src = coef + (size_t)j * KFULL + ig * 64;
        float k0sum = 0.f;
        #pragma unroll
        for (int i = 0; i < 8; ++i) {
            const float4 f0 = *(const float4*)(src + i * 8);
            const float4 f1 = *(const float4*)(src + i * 8 + 4);
            k0sum += f0.x;
            tmp[i*7+0] = f2bf(f0.y); tmp[i*7+1] = f2bf(f0.z); tmp[i*7+2] = f2bf(f0.w);
            tmp[i*7+3] = f2bf(f1.x); tmp[i*7+4] = f2bf(f1.y);
            tmp[i*7+5] = f2bf(f1.z); tmp[i*7+6] = f2bf(f1.w);
        }
        #pragma unroll
        for (int off = 32; off > 0; off >>= 1) k0sum += __shfl_down(k0sum, off, 64);
        if ((t & 63) == 0) redbuf[t >> 6] = k0sum;
    } else {
        const int bb = (blk - CVT_BLOCKS) * 2 + rl;
        const float tr = trp[0];
        const float* xp = x + (size_t)bb * 1024 + ig * 8;
        const float4 x0 = *(const float4*)xp;
        const float4 x1 = *(const float4*)(xp + 4);
        const float xs[8] = {x0.x, x0.y, x0.z, x0.w, x1.x, x1.y, x1.z, x1.w};
        #pragma unroll
        for (int i = 0; i < 8; ++i) {
            const float e  = __expf(2.0f * tr * xs[i]);
            const float tt = 1.0f - 2.0f * __builtin_amdgcn_rcpf(e + 1.0f);  // tanh(tr*x)
            float pw = tt;
            #pragma unroll
            for (int k = 1; k < 8; ++k) { tmp[i * 7 + k - 1] = f2bf(pw); pw *= tt; }
        }
    }

    #pragma unroll
    for (int v = 0; v < 7; ++v)
        *(bf16x8*)&st[t * 56 + v * 8] = *(bf16x8*)&tmp[v * 8];

    __syncthreads();

    if (is_cvt) {
        if (t == 0)   bias[blk * 2]     = redbuf[0] + redbuf[1];
        if (t == 128) bias[blk * 2 + 1] = redbuf[2] + redbuf[3];
    }

    unsigned short* dstbase = is_cvt
        ? coef_bf + (size_t)(blk * 2) * KT
        : A       + (size_t)((blk - CVT_BLOCKS) * 2) * KT;
    #pragma unroll
    for (int v = 0; v < 7; ++v) {
        const int c   = v * 256 + t;
        const int row = c / 896;
        const int cc  = c - row * 896;
        const int igs = cc / 7;
        const int q   = cc - igs * 7;
        const bf16x8 pk = *(const bf16x8*)&st[(row * 128 + igs) * 56 + q * 8];
        *(bf16x8*)(dstbase + (size_t)c * 8) = pk;   // contiguous across threads
    }
}

// ---- pass 2: NT GEMM (K=7168), BK=128 ----
__global__ __launch_bounds__(256, 2)
void gemm_bt(const unsigned short* __restrict__ A, const unsigned short* __restrict__ Bt,
             const float* __restrict__ bias, float* __restrict__ out)
{
    __shared__ unsigned short As[BM * BK];   // 32 KB
    __shared__ unsigned short Bs[BN * BK];   // 32 KB

    const int t    = threadIdx.x;
    const int n0   = blockIdx.x * BN;   // x = n-tile (8) -> XCD-local B slice
    const int m0   = blockIdx.y * BM;
    const int w    = t >> 6;
    const int lane = t & 63;
    const int wm   = (w >> 1) * 64;
    const int wn   = (w & 1) * 64;
    const int lrow = lane & 15;

    // staging: thread t covers row srow + r*16 (r=0..7); fetches swizzled
    // chunk schunk = (t&15)^srow so LDS slot s of row m holds chunk s^(m&15).
    const int srow   = t >> 4;           // 0..15
    const int schunk = (t & 15) ^ srow;
    const int wbase  = w * 512;          // ushort units; +lane*8 applied by HW

    f32x4 acc[4][4];
    #pragma unroll
    for (int i = 0; i < 4; i++)
        #pragma unroll
        for (int j = 0; j < 4; j++)
            acc[i][j] = (f32x4){0.f, 0.f, 0.f, 0.f};

    const size_t abase = (size_t)(m0 + srow) * KT + schunk * 8;
    const size_t bbase = (size_t)(n0 + srow) * KT + schunk * 8;

    for (int k0 = 0; k0 < KT; k0 += BK) {
        #pragma unroll
        for (int r = 0; r < 8; ++r)
            gload_lds16(A + abase + (size_t)r * 16 * KT + k0, &As[r * 2048 + wbase]);
        #pragma unroll
        for (int r = 0; r < 8; ++r)
            gload_lds16(Bt + bbase + (size_t)r * 16 * KT + k0, &Bs[r * 2048 + wbase]);

        __syncthreads();

        #pragma unroll
        for (int kk = 0; kk < BK; kk += 32) {
            // global chunk c = kk/8 + quad; stored at slot c^(m&15), m&15 == lane&15
            const int soff = ((((kk >> 3) + (lane >> 4)) ^ (lane & 15)) * 8);
            bf16x8 a[4], b[4];
            #pragma unroll
            for (int i = 0; i < 4; i++)
                a[i] = *(const bf16x8*)&As[(wm + i * 16 + lrow) * BK + soff];
            #pragma unroll
            for (int j = 0; j < 4; j++)
                b[j] = *(const bf16x8*)&Bs[(wn + j * 16 + lrow) * BK + soff];
            #pragma unroll
            for (int i = 0; i < 4; i++)
                #pragma unroll
                for (int j = 0; j < 4; j++)
                    acc[i][j] = __builtin_amdgcn_mfma_f32_16x16x32_bf16(a[i], b[j], acc[i][j], 0, 0, 0);
        }

        __syncthreads();
    }

    const int crow = (lane >> 4) * 4;
    const int ccol = lane & 15;
    #pragma unroll
    for (int j = 0; j < 4; j++) {
        const int n = n0 + wn + j * 16 + ccol;
        const float bv = bias[n];
        #pragma unroll
        for (int i = 0; i < 4; i++) {
            const int m = m0 + wm + i * 16 + crow;
            #pragma unroll
            for (int r = 0; r < 4; ++r)
                out[(size_t)(m + r) * 1024 + n] = acc[i][j][r] + bv;
        }
    }
}

// ---- fallback: fused kernel (full K=8192), used only if ws too small ----
#define LDK 72
__global__ __launch_bounds__(256, 2)
void taylor_gemm(const float* __restrict__ x, const float* __restrict__ trp,
                 const float* __restrict__ coef, float* __restrict__ out)
{
    __shared__ unsigned short As[BM * LDK];
    __shared__ unsigned short Bs[BN * LDK];

    const int t  = threadIdx.x;
    const int m0 = blockIdx.x * BM;
    const int n0 = blockIdx.y * BN;
    const float tr = trp[0];

    const int w    = t >> 6;
    const int lane = t & 63;
    const int wm   = (w >> 1) * 64;
    const int wn   = (w & 1) * 64;
    const int lrow = lane & 15;
    const int kq   = (lane >> 4) * 8;

    f32x4 acc[4][4];
    #pragma unroll
    for (int i = 0; i < 4; i++)
        #pragma unroll
        for (int j = 0; j < 4; j++)
            acc[i][j] = (f32x4){0.f, 0.f, 0.f, 0.f};

    const int bcol  = t & 15;
    const int brow0 = t >> 4;
    const int acol  = t & 7;
    const int arow0 = t >> 3;

    for (int k0 = 0; k0 < KFULL; k0 += 64) {
        const int i0 = k0 >> 3;
        #pragma unroll
        for (int r = 0; r < 8; ++r) {
            const int row = brow0 + r * 16;
            const float4 v = *(const float4*)(coef + (size_t)(n0 + row) * KFULL + k0 + bcol * 4);
            bf16x4 pk;
            pk[0] = (short)f2bf(v.x); pk[1] = (short)f2bf(v.y);
            pk[2] = (short)f2bf(v.z); pk[3] = (short)f2bf(v.w);
            *(bf16x4*)&Bs[row * LDK + bcol * 4] = pk;
        }
        #pragma unroll
        for (int r = 0; r < 4; ++r) {
            const int row = arow0 + r * 32;
            const float xv = x[(size_t)(m0 + row) * 1024 + i0 + acol];
            const float e  = __expf(2.0f * tr * xv);
            const float tt = 1.0f - 2.0f / (e + 1.0f);
            bf16x8 pk;
            float p = 1.0f;
            #pragma unroll
            for (int k = 0; k < 8; ++k) { pk[k] = (short)f2bf(p); p *= tt; }
            *(bf16x8*)&As[row * LDK + acol * 8] = pk;
        }
        __syncthreads();
        #pragma unroll
        for (int kk = 0; kk < 64; kk += 32) {
            bf16x8 a[4], b[4];
            #pragma unroll
            for (int i = 0; i < 4; i++)
                a[i] = *(const bf16x8*)&As[(wm + i * 16 + lrow) * LDK + kk + kq];
            #pragma unroll
            for (int j = 0; j < 4; j++)
                b[j] = *(const bf16x8*)&Bs[(wn + j * 16 + lrow) * LDK + kk + kq];
            #pragma unroll
            for (int i = 0; i < 4; i++)
                #pragma unroll
                for (int j = 0; j < 4; j++)
                    acc[i][j] = __builtin_amdgcn_mfma_f32_16x16x32_bf16(a[i], b[j], acc[i][j], 0, 0, 0);
        }
        __syncthreads();
    }

    const int crow = (lane >> 4) * 4;
    const int ccol = lane & 15;
    #pragma unroll
    for (int i = 0; i < 4; i++) {
        #pragma unroll
        for (int j = 0; j < 4; j++) {
            const int m = m0 + wm + i * 16 + crow;
            const int n = n0 + wn + j * 16 + ccol;
            #pragma unroll
            for (int r = 0; r < 4; ++r)
                out[(size_t)(m + r) * 1024 + n] = acc[i][j][r];
        }
    }
}

extern "C" void kernel_launch(void* const* d_in, const int* in_sizes, int n_in,
                              void* d_out, int out_size, void* d_ws, size_t ws_size,
                              hipStream_t stream) {
    const float* x    = (const float*)d_in[0];
    const float* trp  = (const float*)d_in[1];
    const float* coef = (const float*)d_in[2];
    float* out = (float*)d_out;

    const size_t A_BYTES    = (size_t)8192 * KT * 2;   // 117,440,512
    const size_t COEF_BYTES = (size_t)1024 * KT * 2;   //  14,680,064
    const size_t BIAS_BYTES = 1024 * sizeof(float);
    dim3 block(256);

    if (ws_size >= A_BYTES + COEF_BYTES + BIAS_BYTES) {
        unsigned short* A_bf    = (unsigned short*)d_ws;
        unsigned short* coef_bf = (unsigned short*)((char*)d_ws + A_BYTES);
        float*          bias    = (float*)((char*)d_ws + A_BYTES + COEF_BYTES);

        prep<<<dim3(CVT_BLOCKS + TANH_BLOCKS), block, 0, stream>>>(
            x, trp, coef, coef_bf, A_bf, bias);
        gemm_bt<<<dim3(1024 / BN, 8192 / BM), block, 0, stream>>>(
            A_bf, coef_bf, bias, out);
    } else {
        taylor_gemm<<<dim3(8192 / BM, 1024 / BN), block, 0, stream>>>(x, trp, coef, out);
    }
}

// Round 8
// 231.025 us; speedup vs baseline: 1.1860x; 1.1860x over previous
//
#include <hip/hip_runtime.h>
#include <hip/hip_bf16.h>

// out[b,j] = sum_{i,k} coef[j,i,k] * tanh(x[b,i])^k
// B=8192, IN=1024, OUT=1024, ORDER=7.
// k=0 plane -> per-j bias (computed in prep, added in gemm epilogue).
// GEMM: M=8192, N=1024, K=IN*7=7168, bf16 MFMA.
//
// Round 8: BK=128 kept (64 MFMA per barrier-pair), grid orientation RESTORED
// to round-6 (blockIdx.x = m-tile): the 8 blocks sharing an A m-tile have
// ids x+64y = x (mod 8) -> same XCD -> A tile fetched once into that XCD's
// L2 (round-7's swap put sharers on 8 different XCDs: FETCH 115->470 MB,
// memory-bound 3.3 TB/s).
// XOR swizzle (16 chunks/row): slot s of row m holds global chunk s^(m&15).

#define BM 128
#define BN 128
#define BK 128
#define KT 7168
#define KFULL 8192

typedef short bf16x8 __attribute__((ext_vector_type(8)));
typedef short bf16x4 __attribute__((ext_vector_type(4)));
typedef float f32x4  __attribute__((ext_vector_type(4)));

__device__ __forceinline__ unsigned short f2bf(float f) {
    union { float f; unsigned u; } v; v.f = f;
    unsigned r = v.u + 0x7fffu + ((v.u >> 16) & 1u);   // RTE
    return (unsigned short)(r >> 16);
}

__device__ __forceinline__ void gload_lds16(const void* gp, void* lp) {
    __builtin_amdgcn_global_load_lds(
        (const __attribute__((address_space(1))) void*)gp,
        (__attribute__((address_space(3))) void*)lp, 16, 0, 0);
}

// ---- pass 1: prep (unchanged from round 6) ----
#define CVT_BLOCKS  512
#define TANH_BLOCKS 4096

__global__ __launch_bounds__(256)
void prep(const float* __restrict__ x, const float* __restrict__ trp,
          const float* __restrict__ coef, unsigned short* __restrict__ coef_bf,
          unsigned short* __restrict__ A, float* __restrict__ bias) {
    __shared__ unsigned short st[256 * 56];   // 28672 B
    __shared__ float redbuf[4];

    const int t   = threadIdx.x;
    const int blk = blockIdx.x;
    const int rl  = t >> 7;        // row_local 0/1
    const int ig  = t & 127;       // i-group (8 i's each)
    const bool is_cvt = (blk < CVT_BLOCKS);

    unsigned short tmp[56];

    if (is_cvt) {
        const int j = blk * 2 + rl;
        const float* src = coef + (size_t)j * KFULL + ig * 64;
        float k0sum = 0.f;
        #pragma unroll
        for (int i = 0; i < 8; ++i) {
            const float4 f0 = *(const float4*)(src + i * 8);
            const float4 f1 = *(const float4*)(src + i * 8 + 4);
            k0sum += f0.x;
            tmp[i*7+0] = f2bf(f0.y); tmp[i*7+1] = f2bf(f0.z); tmp[i*7+2] = f2bf(f0.w);
            tmp[i*7+3] = f2bf(f1.x); tmp[i*7+4] = f2bf(f1.y);
            tmp[i*7+5] = f2bf(f1.z); tmp[i*7+6] = f2bf(f1.w);
        }
        #pragma unroll
        for (int off = 32; off > 0; off >>= 1) k0sum += __shfl_down(k0sum, off, 64);
        if ((t & 63) == 0) redbuf[t >> 6] = k0sum;
    } else {
        const int bb = (blk - CVT_BLOCKS) * 2 + rl;
        const float tr = trp[0];
        const float* xp = x + (size_t)bb * 1024 + ig * 8;
        const float4 x0 = *(const float4*)xp;
        const float4 x1 = *(const float4*)(xp + 4);
        const float xs[8] = {x0.x, x0.y, x0.z, x0.w, x1.x, x1.y, x1.z, x1.w};
        #pragma unroll
        for (int i = 0; i < 8; ++i) {
            const float e  = __expf(2.0f * tr * xs[i]);
            const float tt = 1.0f - 2.0f * __builtin_amdgcn_rcpf(e + 1.0f);  // tanh(tr*x)
            float pw = tt;
            #pragma unroll
            for (int k = 1; k < 8; ++k) { tmp[i * 7 + k - 1] = f2bf(pw); pw *= tt; }
        }
    }

    #pragma unroll
    for (int v = 0; v < 7; ++v)
        *(bf16x8*)&st[t * 56 + v * 8] = *(bf16x8*)&tmp[v * 8];

    __syncthreads();

    if (is_cvt) {
        if (t == 0)   bias[blk * 2]     = redbuf[0] + redbuf[1];
        if (t == 128) bias[blk * 2 + 1] = redbuf[2] + redbuf[3];
    }

    unsigned short* dstbase = is_cvt
        ? coef_bf + (size_t)(blk * 2) * KT
        : A       + (size_t)((blk - CVT_BLOCKS) * 2) * KT;
    #pragma unroll
    for (int v = 0; v < 7; ++v) {
        const int c   = v * 256 + t;
        const int row = c / 896;
        const int cc  = c - row * 896;
        const int igs = cc / 7;
        const int q   = cc - igs * 7;
        const bf16x8 pk = *(const bf16x8*)&st[(row * 128 + igs) * 56 + q * 8];
        *(bf16x8*)(dstbase + (size_t)c * 8) = pk;   // contiguous across threads
    }
}

// ---- pass 2: NT GEMM (K=7168), BK=128, round-6 grid orientation ----
__global__ __launch_bounds__(256, 2)
void gemm_bt(const unsigned short* __restrict__ A, const unsigned short* __restrict__ Bt,
             const float* __restrict__ bias, float* __restrict__ out)
{
    __shared__ unsigned short As[BM * BK];   // 32 KB
    __shared__ unsigned short Bs[BN * BK];   // 32 KB

    const int t    = threadIdx.x;
    const int m0   = blockIdx.x * BM;   // x = m-tile: A-sharers land on same XCD
    const int n0   = blockIdx.y * BN;
    const int w    = t >> 6;
    const int lane = t & 63;
    const int wm   = (w >> 1) * 64;
    const int wn   = (w & 1) * 64;
    const int lrow = lane & 15;

    // staging: thread t covers row srow + r*16 (r=0..7); fetches swizzled
    // chunk schunk = (t&15)^srow so LDS slot s of row m holds chunk s^(m&15).
    const int srow   = t >> 4;           // 0..15
    const int schunk = (t & 15) ^ srow;
    const int wbase  = w * 512;          // ushort units; +lane*8 applied by HW

    f32x4 acc[4][4];
    #pragma unroll
    for (int i = 0; i < 4; i++)
        #pragma unroll
        for (int j = 0; j < 4; j++)
            acc[i][j] = (f32x4){0.f, 0.f, 0.f, 0.f};

    const size_t abase = (size_t)(m0 + srow) * KT + schunk * 8;
    const size_t bbase = (size_t)(n0 + srow) * KT + schunk * 8;

    for (int k0 = 0; k0 < KT; k0 += BK) {
        #pragma unroll
        for (int r = 0; r < 8; ++r)
            gload_lds16(A + abase + (size_t)r * 16 * KT + k0, &As[r * 2048 + wbase]);
        #pragma unroll
        for (int r = 0; r < 8; ++r)
            gload_lds16(Bt + bbase + (size_t)r * 16 * KT + k0, &Bs[r * 2048 + wbase]);

        __syncthreads();

        #pragma unroll
        for (int kk = 0; kk < BK; kk += 32) {
            // global chunk c = kk/8 + quad; stored at slot c^(m&15), m&15 == lane&15
            const int soff = ((((kk >> 3) + (lane >> 4)) ^ (lane & 15)) * 8);
            bf16x8 a[4], b[4];
            #pragma unroll
            for (int i = 0; i < 4; i++)
                a[i] = *(const bf16x8*)&As[(wm + i * 16 + lrow) * BK + soff];
            #pragma unroll
            for (int j = 0; j < 4; j++)
                b[j] = *(const bf16x8*)&Bs[(wn + j * 16 + lrow) * BK + soff];
            #pragma unroll
            for (int i = 0; i < 4; i++)
                #pragma unroll
                for (int j = 0; j < 4; j++)
                    acc[i][j] = __builtin_amdgcn_mfma_f32_16x16x32_bf16(a[i], b[j], acc[i][j], 0, 0, 0);
        }

        __syncthreads();
    }

    const int crow = (lane >> 4) * 4;
    const int ccol = lane & 15;
    #pragma unroll
    for (int j = 0; j < 4; j++) {
        const int n = n0 + wn + j * 16 + ccol;
        const float bv = bias[n];
        #pragma unroll
        for (int i = 0; i < 4; i++) {
            const int m = m0 + wm + i * 16 + crow;
            #pragma unroll
            for (int r = 0; r < 4; ++r)
                out[(size_t)(m + r) * 1024 + n] = acc[i][j][r] + bv;
        }
    }
}

// ---- fallback: fused kernel (full K=8192), used only if ws too small ----
#define LDK 72
__global__ __launch_bounds__(256, 2)
void taylor_gemm(const float* __restrict__ x, const float* __restrict__ trp,
                 const float* __restrict__ coef, float* __restrict__ out)
{
    __shared__ unsigned short As[BM * LDK];
    __shared__ unsigned short Bs[BN * LDK];

    const int t  = threadIdx.x;
    const int m0 = blockIdx.x * BM;
    const int n0 = blockIdx.y * BN;
    const float tr = trp[0];

    const int w    = t >> 6;
    const int lane = t & 63;
    const int wm   = (w >> 1) * 64;
    const int wn   = (w & 1) * 64;
    const int lrow = lane & 15;
    const int kq   = (lane >> 4) * 8;

    f32x4 acc[4][4];
    #pragma unroll
    for (int i = 0; i < 4; i++)
        #pragma unroll
        for (int j = 0; j < 4; j++)
            acc[i][j] = (f32x4){0.f, 0.f, 0.f, 0.f};

    const int bcol  = t & 15;
    const int brow0 = t >> 4;
    const int acol  = t & 7;
    const int arow0 = t >> 3;

    for (int k0 = 0; k0 < KFULL; k0 += 64) {
        const int i0 = k0 >> 3;
        #pragma unroll
        for (int r = 0; r < 8; ++r) {
            const int row = brow0 + r * 16;
            const float4 v = *(const float4*)(coef + (size_t)(n0 + row) * KFULL + k0 + bcol * 4);
            bf16x4 pk;
            pk[0] = (short)f2bf(v.x); pk[1] = (short)f2bf(v.y);
            pk[2] = (short)f2bf(v.z); pk[3] = (short)f2bf(v.w);
            *(bf16x4*)&Bs[row * LDK + bcol * 4] = pk;
        }
        #pragma unroll
        for (int r = 0; r < 4; ++r) {
            const int row = arow0 + r * 32;
            const float xv = x[(size_t)(m0 + row) * 1024 + i0 + acol];
            const float e  = __expf(2.0f * tr * xv);
            const float tt = 1.0f - 2.0f / (e + 1.0f);
            bf16x8 pk;
            float p = 1.0f;
            #pragma unroll
            for (int k = 0; k < 8; ++k) { pk[k] = (short)f2bf(p); p *= tt; }
            *(bf16x8*)&As[row * LDK + acol * 8] = pk;
        }
        __syncthreads();
        #pragma unroll
        for (int kk = 0; kk < 64; kk += 32) {
            bf16x8 a[4], b[4];
            #pragma unroll
            for (int i = 0; i < 4; i++)
                a[i] = *(const bf16x8*)&As[(wm + i * 16 + lrow) * LDK + kk + kq];
            #pragma unroll
            for (int j = 0; j < 4; j++)
                b[j] = *(const bf16x8*)&Bs[(wn + j * 16 + lrow) * LDK + kk + kq];
            #pragma unroll
            for (int i = 0; i < 4; i++)
                #pragma unroll
                for (int j = 0; j < 4; j++)
                    acc[i][j] = __builtin_amdgcn_mfma_f32_16x16x32_bf16(a[i], b[j], acc[i][j], 0, 0, 0);
        }
        __syncthreads();
    }

    const int crow = (lane >> 4) * 4;
    const int ccol = lane & 15;
    #pragma unroll
    for (int i = 0; i < 4; i++) {
        #pragma unroll
        for (int j = 0; j < 4; j++) {
            const int m = m0 + wm + i * 16 + crow;
            const int n = n0 + wn + j * 16 + ccol;
            #pragma unroll
            for (int r = 0; r < 4; ++r)
                out[(size_t)(m + r) * 1024 + n] = acc[i][j][r];
        }
    }
}

extern "C" void kernel_launch(void* const* d_in, const int* in_sizes, int n_in,
                              void* d_out, int out_size, void* d_ws, size_t ws_size,
                              hipStream_t stream) {
    const float* x    = (const float*)d_in[0];
    const float* trp  = (const float*)d_in[1];
    const float* coef = (const float*)d_in[2];
    float* out = (float*)d_out;

    const size_t A_BYTES    = (size_t)8192 * KT * 2;   // 117,440,512
    const size_t COEF_BYTES = (size_t)1024 * KT * 2;   //  14,680,064
    const size_t BIAS_BYTES = 1024 * sizeof(float);
    dim3 block(256);

    if (ws_size >= A_BYTES + COEF_BYTES + BIAS_BYTES) {
        unsigned short* A_bf    = (unsigned short*)d_ws;
        unsigned short* coef_bf = (unsigned short*)((char*)d_ws + A_BYTES);
        float*          bias    = (float*)((char*)d_ws + A_BYTES + COEF_BYTES);

        prep<<<dim3(CVT_BLOCKS + TANH_BLOCKS), block, 0, stream>>>(
            x, trp, coef, coef_bf, A_bf, bias);
        gemm_bt<<<dim3(8192 / BM, 1024 / BN), block, 0, stream>>>(
            A_bf, coef_bf, bias, out);
    } else {
        taylor_gemm<<<dim3(8192 / BM, 1024 / BN), block, 0, stream>>>(x, trp, coef, out);
    }
}